// Round 7
// baseline (485.086 us; speedup 1.0000x reference)
//
#include <hip/hip_runtime.h>

typedef __attribute__((ext_vector_type(4))) float f32x4;
typedef __attribute__((ext_vector_type(8))) short bf16x8;

#define HIST_RANGE 8192   // per-class LDS histogram capacity (supports n <= 65536 with 8 classes)

// ---------------- edge-index detection + conversion ----------------

__global__ void k_detect(const unsigned int* ei, int* flag) {
    if (blockIdx.x == 0 && threadIdx.x == 0) {
        int is64 = 1;
        for (int i = 0; i < 64; ++i) {
            if (ei[2 * i + 1] != 0u) { is64 = 0; break; }
        }
        *flag = is64;
    }
}

__global__ void k_convert(const void* ei, int twoE, const int* flag, int* __restrict__ out) {
    int i = blockIdx.x * blockDim.x + threadIdx.x;
    if (i >= twoE) return;
    int v;
    if (*flag) v = (int)((const long long*)ei)[i];
    else       v = ((const int*)ei)[i];
    out[i] = v;
}

// fallback histogram (n > 8*HIST_RANGE): global atomics
__global__ void k_hist_atomic(const int* __restrict__ dst, int E, int* __restrict__ cnt) {
    int e = blockIdx.x * blockDim.x + threadIdx.x;
    if (e < E) atomicAdd(&cnt[dst[e]], 1);
}

// ---------------- LDS-privatized, dst-range-partitioned histogram ----------------
// block b: class = b&7 (dst range), rep = b>>3 (edge chunk). No global atomics.

__global__ __launch_bounds__(256) void k_hist_part(
    const int* __restrict__ dst, int E, int n, int nrep, int* __restrict__ partial)
{
    __shared__ int h[HIST_RANGE];
    const int cls = blockIdx.x & 7;
    const int rep = blockIdx.x >> 3;
    const int range = (n + 7) >> 3;
    const int lo = cls * range;
    const int hi = min(n, lo + range);
    const int cr = hi - lo;
    if (cr <= 0) return;
    for (int i = threadIdx.x; i < cr; i += 256) h[i] = 0;
    __syncthreads();
    const int chunk = (E + nrep - 1) / nrep;
    const int ebeg = rep * chunk;
    const int eend = min(E, ebeg + chunk);
    for (int e = ebeg + (int)threadIdx.x; e < eend; e += 256) {
        int d = __builtin_nontemporal_load(&dst[e]);
        if (d >= lo && d < hi) atomicAdd(&h[d - lo], 1);
    }
    __syncthreads();
    int* po = partial + (size_t)rep * n + lo;
    for (int i = threadIdx.x; i < cr; i += 256) po[i] = h[i];
}

// ---------------- parallel scan: sum partials -> cnt, exclusive scan -> rowptr ----------------

__global__ __launch_bounds__(512) void k_scan1(
    const int* __restrict__ partial, int nrep, int n,
    int* __restrict__ cnt, int* __restrict__ rowptr, int* __restrict__ bsum)
{
    __shared__ int part[512];
    const int t = threadIdx.x;
    const int i = blockIdx.x * 512 + t;
    int own = 0;
    if (i < n) {
        for (int r = 0; r < nrep; ++r) own += partial[(size_t)r * n + i];
        cnt[i] = own;
    }
    part[t] = own;
    __syncthreads();
#pragma unroll
    for (int off = 1; off < 512; off <<= 1) {
        int v = (t >= off) ? part[t - off] : 0;
        __syncthreads();
        part[t] += v;
        __syncthreads();
    }
    if (i < n) rowptr[i] = part[t] - own;
    if (t == 511) bsum[blockIdx.x] = part[511];
}

__global__ __launch_bounds__(256) void k_scan2(const int* __restrict__ bsum, int nb,
                                               int* __restrict__ bofs) {
    __shared__ int part[256];
    const int t = threadIdx.x;
    int own = (t < nb) ? bsum[t] : 0;
    part[t] = own;
    __syncthreads();
#pragma unroll
    for (int off = 1; off < 256; off <<= 1) {
        int v = (t >= off) ? part[t - off] : 0;
        __syncthreads();
        part[t] += v;
        __syncthreads();
    }
    if (t < nb) bofs[t] = part[t] - own;
}

// adds block offsets; cursor starts at rowptr (fill indexes csr via cursor alone)
__global__ void k_scan3(const int* __restrict__ cnt, int n, int E,
                        const int* __restrict__ bofs, int* __restrict__ rowptr,
                        int* __restrict__ cursor, float* __restrict__ dinv) {
    int i = blockIdx.x * blockDim.x + threadIdx.x;
    if (i >= n) return;
    int rp = rowptr[i] + bofs[i >> 9];
    rowptr[i] = rp;
    cursor[i] = rp;
    dinv[i] = rsqrtf((float)(cnt[i] + 1));
    if (i == 0) rowptr[n] = E;
}

// ---------------- CSR fill, dst-range partitioned + nt streaming loads ----------------

__global__ __launch_bounds__(256) void k_fill_part(
    const int* __restrict__ src, const int* __restrict__ dst, int E, int n,
    int* __restrict__ cursor, int* __restrict__ csr)
{
    const int range = blockIdx.x & 7;
    const int chunk = blockIdx.x >> 3;
    const int nchunks = gridDim.x >> 3;
    const int lo = (int)(((long long)n * range) >> 3);
    const int hi = (int)(((long long)n * (range + 1)) >> 3);
    for (int e = chunk * 256 + (int)threadIdx.x; e < E; e += nchunks * 256) {
        int d = __builtin_nontemporal_load(&dst[e]);
        if (d >= lo && d < hi) {
            int s = __builtin_nontemporal_load(&src[e]);
            int pos = atomicAdd(&cursor[d], 1);
            csr[pos] = s;
        }
    }
}

// ---------------- weight conversion: fp32 [K,F] -> fragment-ordered bf16 hi/lo ----------------

__global__ void k_wconv(const float* __restrict__ W, int K, int F,
                        unsigned short* __restrict__ WH, unsigned short* __restrict__ WL) {
    int idx = blockIdx.x * blockDim.x + threadIdx.x;
    int total = (K / 32) * (F / 16) * 64;
    if (idx >= total) return;
    int lane = idx & 63;
    int t = idx >> 6;
    int CT = F / 16;
    int ks = t / CT, ct = t % CT;
    int col = ct * 16 + (lane & 15);
    int kbase = ks * 32 + (lane >> 4) * 8;
    bf16x8 h, l;
#pragma unroll
    for (int j = 0; j < 8; ++j) {
        float w = W[(size_t)(kbase + j) * F + col];
        unsigned int u = __float_as_uint(w);
        unsigned short hi = (unsigned short)(u >> 16);
        float r = w - __uint_as_float((unsigned int)hi << 16);
        unsigned short lo = (unsigned short)(__float_as_uint(r) >> 16);
        h[j] = (short)hi;
        l[j] = (short)lo;
    }
    *(bf16x8*)(WH + (size_t)idx * 8) = h;
    *(bf16x8*)(WL + (size_t)idx * 8) = l;
}

// ---------------- MFMA GEMM (split-bf16, fp32-accurate) ----------------

template<int K, int F, int OMODE, bool RELU, bool BIAS, bool SUM2, bool POSTADD>
__global__ __launch_bounds__(256) void k_mgemm(
    const float* __restrict__ A0, const float* __restrict__ A1, const float* __restrict__ A2,
    const unsigned short* __restrict__ WH, const unsigned short* __restrict__ WL,
    const float* __restrict__ bias, const float* __restrict__ post,
    const float* __restrict__ dinv, void* __restrict__ outv, int n)
{
    constexpr int CT = F / 16;
    const int lane = threadIdx.x & 63;
    const int wave = threadIdx.x >> 6;
    const int row0 = blockIdx.x * 128 + wave * 32;
    const int arow = lane & 15;
    const int kgrp = lane >> 4;

    f32x4 acc[2][CT];
#pragma unroll
    for (int rt = 0; rt < 2; ++rt)
#pragma unroll
        for (int ct = 0; ct < CT; ++ct) acc[rt][ct] = (f32x4)(0.f);

#pragma unroll
    for (int ks = 0; ks < K / 32; ++ks) {
        const float* Ap; int kof;
        if constexpr (K == 128) { Ap = A0; kof = ks * 32; }
        else { int p = ks >> 2; Ap = (p == 0) ? A0 : ((p == 1) ? A1 : A2); kof = (ks & 3) * 32; }

        bf16x8 ah[2], al[2];
#pragma unroll
        for (int rt = 0; rt < 2; ++rt) {
            int row = row0 + rt * 16 + arow;
            if (row >= n) row = n - 1;
            const float* p = Ap + (size_t)row * 128 + kof + kgrp * 8;
            f32x4 v0 = *(const f32x4*)p;
            f32x4 v1 = *(const f32x4*)(p + 4);
            if constexpr (SUM2) {
                const float* q = A1 + (size_t)row * 128 + kof + kgrp * 8;
                f32x4 u0 = *(const f32x4*)q;
                f32x4 u1 = *(const f32x4*)(q + 4);
                v0 += u0; v1 += u1;
            }
#pragma unroll
            for (int j = 0; j < 8; ++j) {
                float f = (j < 4) ? v0[j] : v1[j - 4];
                unsigned int u = __float_as_uint(f);
                unsigned short hi = (unsigned short)(u >> 16);
                float r = f - __uint_as_float((unsigned int)hi << 16);
                ah[rt][j] = (short)hi;
                al[rt][j] = (short)(__float_as_uint(r) >> 16);
            }
        }

#pragma unroll
        for (int ct = 0; ct < CT; ++ct) {
            size_t fo = (((size_t)ks * CT + ct) * 64 + lane) * 8;
            bf16x8 bh = *(const bf16x8*)(WH + fo);
            bf16x8 bl = *(const bf16x8*)(WL + fo);
#pragma unroll
            for (int rt = 0; rt < 2; ++rt) {
                acc[rt][ct] = __builtin_amdgcn_mfma_f32_16x16x32_bf16(ah[rt], bh, acc[rt][ct], 0, 0, 0);
                acc[rt][ct] = __builtin_amdgcn_mfma_f32_16x16x32_bf16(al[rt], bh, acc[rt][ct], 0, 0, 0);
                acc[rt][ct] = __builtin_amdgcn_mfma_f32_16x16x32_bf16(ah[rt], bl, acc[rt][ct], 0, 0, 0);
            }
        }
    }

    // epilogue: D layout col=lane&15, row=(lane>>4)*4+reg  [m89-verified]
    if constexpr (OMODE == 1) {
        unsigned short* ob = (unsigned short*)outv;
        float dv[2][4];
#pragma unroll
        for (int rt = 0; rt < 2; ++rt)
#pragma unroll
            for (int r = 0; r < 4; ++r) {
                int row = row0 + rt * 16 + kgrp * 4 + r;
                dv[rt][r] = (row < n) ? dinv[row] : 0.f;
            }
#pragma unroll
        for (int rt = 0; rt < 2; ++rt) {
#pragma unroll
            for (int ct = 0; ct < CT; ++ct) {
                int j = ct * 16 + arow;
#pragma unroll
                for (int r = 0; r < 4; ++r) {
                    int row = row0 + rt * 16 + kgrp * 4 + r;
                    if (row < n) {
                        float v = acc[rt][ct][r] * dv[rt][r];
                        unsigned int u = __float_as_uint(v);
                        u += 0x7fffu + ((u >> 16) & 1u);        // RNE
                        ob[(size_t)row * F + j] = (unsigned short)(u >> 16);
                    }
                }
            }
        }
    } else {
        float* ofp = (float*)outv;
#pragma unroll
        for (int rt = 0; rt < 2; ++rt) {
#pragma unroll
            for (int ct = 0; ct < CT; ++ct) {
                int j = ct * 16 + arow;
                float bv = 0.f;
                if constexpr (BIAS) bv = bias[j];
#pragma unroll
                for (int r = 0; r < 4; ++r) {
                    int row = row0 + rt * 16 + kgrp * 4 + r;
                    if (row < n) {
                        float v = acc[rt][ct][r];
                        if constexpr (BIAS) v += bv;
                        if constexpr (RELU) v = fmaxf(v, 0.f);
                        if constexpr (POSTADD) v += post[(size_t)row * F + j];
                        ofp[(size_t)row * F + j] = v;
                    }
                }
            }
        }
    }
}

// ---------------- GCN aggregation over pre-scaled bf16 features ----------------

__global__ __launch_bounds__(256) void k_agg_bf(
    const int* __restrict__ rowptr, const int* __restrict__ csr,
    const float* __restrict__ dinv, const unsigned short* __restrict__ hs,
    const float* __restrict__ bias, float* __restrict__ out, int n)
{
    const int node = blockIdx.x * 8 + (threadIdx.x >> 5);
    if (node >= n) return;
    const int c = threadIdx.x & 31;
    const float dd = dinv[node];
    const int beg = rowptr[node];
    const int end = rowptr[node + 1];

    ushort4 sv = *(const ushort4*)(hs + (size_t)node * 128 + c * 4);
    float a0 = __uint_as_float((unsigned int)sv.x << 16);
    float a1 = __uint_as_float((unsigned int)sv.y << 16);
    float a2 = __uint_as_float((unsigned int)sv.z << 16);
    float a3 = __uint_as_float((unsigned int)sv.w << 16);

    int j = beg;
    for (; j + 3 < end; j += 4) {
        int s0 = csr[j], s1 = csr[j + 1], s2 = csr[j + 2], s3 = csr[j + 3];
        ushort4 v0 = *(const ushort4*)(hs + (size_t)s0 * 128 + c * 4);
        ushort4 v1 = *(const ushort4*)(hs + (size_t)s1 * 128 + c * 4);
        ushort4 v2 = *(const ushort4*)(hs + (size_t)s2 * 128 + c * 4);
        ushort4 v3 = *(const ushort4*)(hs + (size_t)s3 * 128 + c * 4);
        a0 += __uint_as_float((unsigned int)v0.x << 16);
        a1 += __uint_as_float((unsigned int)v0.y << 16);
        a2 += __uint_as_float((unsigned int)v0.z << 16);
        a3 += __uint_as_float((unsigned int)v0.w << 16);
        a0 += __uint_as_float((unsigned int)v1.x << 16);
        a1 += __uint_as_float((unsigned int)v1.y << 16);
        a2 += __uint_as_float((unsigned int)v1.z << 16);
        a3 += __uint_as_float((unsigned int)v1.w << 16);
        a0 += __uint_as_float((unsigned int)v2.x << 16);
        a1 += __uint_as_float((unsigned int)v2.y << 16);
        a2 += __uint_as_float((unsigned int)v2.z << 16);
        a3 += __uint_as_float((unsigned int)v2.w << 16);
        a0 += __uint_as_float((unsigned int)v3.x << 16);
        a1 += __uint_as_float((unsigned int)v3.y << 16);
        a2 += __uint_as_float((unsigned int)v3.z << 16);
        a3 += __uint_as_float((unsigned int)v3.w << 16);
    }
    for (; j < end; ++j) {
        int s = csr[j];
        ushort4 v = *(const ushort4*)(hs + (size_t)s * 128 + c * 4);
        a0 += __uint_as_float((unsigned int)v.x << 16);
        a1 += __uint_as_float((unsigned int)v.y << 16);
        a2 += __uint_as_float((unsigned int)v.z << 16);
        a3 += __uint_as_float((unsigned int)v.w << 16);
    }

    float4 bv = ((const float4*)bias)[c];
    float4 o;
    o.x = fmaxf(fmaf(dd, a0, bv.x), 0.f);
    o.y = fmaxf(fmaf(dd, a1, bv.y), 0.f);
    o.z = fmaxf(fmaf(dd, a2, bv.z), 0.f);
    o.w = fmaxf(fmaf(dd, a3, bv.w), 0.f);
    ((float4*)out)[(size_t)node * 32 + c] = o;
}

// ---------------- final small GEMM [n,64]@[64,10] ----------------

__global__ __launch_bounds__(256) void k_final(const float* __restrict__ z7, const float* __restrict__ Wo,
                        const float* __restrict__ bo, float* __restrict__ out, int n) {
    __shared__ float Wos[64][10];
    __shared__ float bos[10];
    if (threadIdx.x < 64) {
#pragma unroll
        for (int j = 0; j < 10; ++j) Wos[threadIdx.x][j] = Wo[threadIdx.x * 10 + j];
        if (threadIdx.x < 10) bos[threadIdx.x] = bo[threadIdx.x];
    }
    __syncthreads();
    int idx = blockIdx.x * blockDim.x + threadIdx.x;
    if (idx >= n * 10) return;
    int row = idx / 10, j = idx % 10;
    const float* zr = z7 + (size_t)row * 64;
    float acc = bos[j];
#pragma unroll
    for (int k = 0; k < 64; ++k) acc = fmaf(zr[k], Wos[k][j], acc);
    out[idx] = acc;
}

// ---------------- launch ----------------

extern "C" void kernel_launch(void* const* d_in, const int* in_sizes, int n_in,
                              void* d_out, int out_size, void* d_ws, size_t ws_size,
                              hipStream_t stream) {
    const float* x   = (const float*)d_in[0];
    const float* gx  = (const float*)d_in[1];
    const void*  ei  = d_in[2];
    const float* W1  = (const float*)d_in[3];  const float* b1  = (const float*)d_in[4];
    const float* Wdr = (const float*)d_in[5];  const float* bdr = (const float*)d_in[6];
    const float* Wg1 = (const float*)d_in[7];  const float* bg1 = (const float*)d_in[8];
    const float* Wg2 = (const float*)d_in[9];  const float* bg2 = (const float*)d_in[10];
    const float* W2  = (const float*)d_in[11]; const float* b2  = (const float*)d_in[12];
    const float* W3  = (const float*)d_in[13]; const float* b3  = (const float*)d_in[14];
    const float* Wo  = (const float*)d_in[15]; const float* bo  = (const float*)d_in[16];
    float* out = (float*)d_out;
    const int n = in_sizes[0] / 128;
    const int E = in_sizes[2] / 2;
    const int twoE = 2 * E;
    const int nb = (n + 511) / 512;
    const int NREP = 32;

    char* ws = (char*)d_ws;
    size_t off = 0;
    auto alloc = [&](size_t bytes) -> void* {
        void* p = ws + off;
        off = (off + bytes + 255) & ~(size_t)255;
        return p;
    };
    int*   flag   = (int*)  alloc(256);
    int*   cnt    = (int*)  alloc((size_t)n * 4);
    int*   rowptr = (int*)  alloc(((size_t)n + 1) * 4);
    int*   cursor = (int*)  alloc((size_t)n * 4);
    float* dinv   = (float*)alloc((size_t)n * 4);
    int*   bsum   = (int*)  alloc(1024);
    int*   bofs   = (int*)  alloc(1024);
    int*   es     = (int*)  alloc((size_t)twoE * 4);
    int*   ed     = es + E;
    int*   csr    = (int*)  alloc((size_t)E * 4);
    int*   partial= (int*)  alloc((size_t)NREP * n * 4);
    unsigned short* W1H  = (unsigned short*)alloc(256 * 128 * 2);
    unsigned short* W1L  = (unsigned short*)alloc(256 * 128 * 2);
    unsigned short* WdrH = (unsigned short*)alloc(128 * 128 * 2);
    unsigned short* WdrL = (unsigned short*)alloc(128 * 128 * 2);
    unsigned short* Wg1H = (unsigned short*)alloc(128 * 128 * 2);
    unsigned short* Wg1L = (unsigned short*)alloc(128 * 128 * 2);
    unsigned short* Wg2H = (unsigned short*)alloc(128 * 128 * 2);
    unsigned short* Wg2L = (unsigned short*)alloc(128 * 128 * 2);
    unsigned short* W2H  = (unsigned short*)alloc(384 * 128 * 2);
    unsigned short* W2L  = (unsigned short*)alloc(384 * 128 * 2);
    unsigned short* W3H  = (unsigned short*)alloc(128 * 64 * 2);
    unsigned short* W3L  = (unsigned short*)alloc(128 * 64 * 2);
    unsigned short* HS1  = (unsigned short*)alloc((size_t)n * 128 * 2);
    unsigned short* HS2  = (unsigned short*)alloc((size_t)n * 128 * 2);
    float* B0 = (float*)alloc((size_t)n * 128 * 4); // z
    float* B1 = (float*)alloc((size_t)n * 128 * 4); // z0 -> z7
    float* B2 = (float*)alloc((size_t)n * 128 * 4); // t
    float* B3 = (float*)alloc((size_t)n * 128 * 4); // z1
    float* B4 = (float*)alloc((size_t)n * 128 * 4); // z2
    (void)ws_size; (void)n_in; (void)out_size;

    // edge prep + CSR build
    k_detect<<<1, 64, 0, stream>>>((const unsigned int*)ei, flag);
    k_convert<<<(twoE + 255) / 256, 256, 0, stream>>>(ei, twoE, flag, es);
    if (n <= 8 * HIST_RANGE) {
        k_hist_part<<<8 * NREP, 256, 0, stream>>>(ed, E, n, NREP, partial);
        k_scan1<<<nb, 512, 0, stream>>>(partial, NREP, n, cnt, rowptr, bsum);
    } else {
        hipMemsetAsync(cnt, 0, (size_t)n * 4, stream);
        k_hist_atomic<<<(E + 255) / 256, 256, 0, stream>>>(ed, E, cnt);
        k_scan1<<<nb, 512, 0, stream>>>(cnt, 1, n, cnt, rowptr, bsum);
    }
    k_scan2<<<1, 256, 0, stream>>>(bsum, nb, bofs);
    k_scan3<<<(n + 255) / 256, 256, 0, stream>>>(cnt, n, E, bofs, rowptr, cursor, dinv);
    k_fill_part<<<2048, 256, 0, stream>>>(es, ed, E, n, cursor, csr);

    // weight conversions (tiny)
    k_wconv<<<(256 * 128 + 255) / 256, 256, 0, stream>>>(W1,  256, 128, W1H,  W1L);
    k_wconv<<<(128 * 128 + 255) / 256, 256, 0, stream>>>(Wdr, 128, 128, WdrH, WdrL);
    k_wconv<<<(128 * 128 + 255) / 256, 256, 0, stream>>>(Wg1, 128, 128, Wg1H, Wg1L);
    k_wconv<<<(128 * 128 + 255) / 256, 256, 0, stream>>>(Wg2, 128, 128, Wg2H, Wg2L);
    k_wconv<<<(384 * 128 + 255) / 256, 256, 0, stream>>>(W2,  384, 128, W2H,  W2L);
    k_wconv<<<(128 * 64  + 255) / 256, 256, 0, stream>>>(W3,  128, 64,  W3H,  W3L);

    const int gm = (n + 127) / 128;
    const int ga = (n + 7) / 8;
    // z = relu([x|gx] @ W1 + b1)
    k_mgemm<256, 128, 0, true,  true,  false, false><<<gm, 256, 0, stream>>>(x, gx, nullptr, W1H, W1L, b1, nullptr, nullptr, B0, n);
    // z0 = z @ Wdr + bdr
    k_mgemm<128, 128, 0, false, true,  false, false><<<gm, 256, 0, stream>>>(B0, nullptr, nullptr, WdrH, WdrL, bdr, nullptr, nullptr, B1, n);
    // hs1 = dinv * ((z + gx) @ Wg1)   [bf16]
    k_mgemm<128, 128, 1, false, false, true,  false><<<gm, 256, 0, stream>>>(B0, gx, nullptr, Wg1H, Wg1L, nullptr, nullptr, dinv, HS1, n);
    // z1 = relu(dinv * (hs1[d] + sum hs1[s]) + bg1)
    k_agg_bf<<<ga, 256, 0, stream>>>(rowptr, csr, dinv, HS1, bg1, B3, n);
    // hs2 = dinv * (z1 @ Wg2)   [bf16]
    k_mgemm<128, 128, 1, false, false, false, false><<<gm, 256, 0, stream>>>(B3, nullptr, nullptr, Wg2H, Wg2L, nullptr, nullptr, dinv, HS2, n);
    // z2 = relu(dinv * (hs2[d] + sum hs2[s]) + bg2)
    k_agg_bf<<<ga, 256, 0, stream>>>(rowptr, csr, dinv, HS2, bg2, B4, n);
    // t = relu([z|z1|z2] @ W2 + b2) + z0
    k_mgemm<384, 128, 0, true,  true,  false, true ><<<gm, 256, 0, stream>>>(B0, B3, B4, W2H, W2L, b2, B1, nullptr, B2, n);
    // z7 = relu(t @ W3 + b3)
    k_mgemm<128, 64,  0, true,  true,  false, false><<<gm, 256, 0, stream>>>(B2, nullptr, nullptr, W3H, W3L, b3, nullptr, nullptr, B1, n);
    // out = z7 @ Wo + bo
    k_final<<<(n * 10 + 255) / 256, 256, 0, stream>>>(B1, Wo, bo, out, n);
}

// Round 9
// 400.914 us; speedup vs baseline: 1.2100x; 1.2100x over previous
//
#include <hip/hip_runtime.h>

typedef __attribute__((ext_vector_type(4))) float f32x4;
typedef __attribute__((ext_vector_type(8))) short bf16x8;
typedef __attribute__((ext_vector_type(4))) int i32x4;

#define HIST_RANGE 8192   // per-class LDS capacity (8 classes -> n <= 65536)

// ---------------- edge-index detection + conversion ----------------

__global__ void k_detect(const unsigned int* ei, int* flag) {
    if (blockIdx.x == 0 && threadIdx.x == 0) {
        int is64 = 1;
        for (int i = 0; i < 64; ++i) {
            if (ei[2 * i + 1] != 0u) { is64 = 0; break; }
        }
        *flag = is64;
    }
}

__global__ void k_convert(const void* ei, int twoE, const int* flag, int* __restrict__ out) {
    int p = blockIdx.x * blockDim.x + threadIdx.x;   // pair index
    int b = p * 2;
    if (b + 1 < twoE) {
        if (*flag) {
            i32x4 v = *(const i32x4*)((const long long*)ei + b);   // 2 x int64
            int2 o; o.x = v.x; o.y = v.z;                          // low words
            *(int2*)(out + b) = o;
        } else {
            *(int2*)(out + b) = *(const int2*)((const int*)ei + b);
        }
    } else if (b < twoE) {
        out[b] = (*flag) ? (int)((const long long*)ei)[b] : ((const int*)ei)[b];
    }
}

// fallback histogram (n > 8*HIST_RANGE): global atomics
__global__ void k_hist_atomic(const int* __restrict__ dst, int E, int* __restrict__ cnt) {
    int e = blockIdx.x * blockDim.x + threadIdx.x;
    if (e < E) atomicAdd(&cnt[dst[e]], 1);
}

// ---------------- LDS-privatized, dst-range-partitioned histogram ----------------
// block b: class = b&7 (dst range), rep = b>>3 (edge chunk). No global atomics.

__global__ __launch_bounds__(256) void k_hist_part(
    const int* __restrict__ dst, int E, int n, int nrep, int* __restrict__ partial)
{
    __shared__ int h[HIST_RANGE];
    const int cls = blockIdx.x & 7;
    const int rep = blockIdx.x >> 3;
    const int range = (n + 7) >> 3;
    const int lo = cls * range;
    const int hi = min(n, lo + range);
    const int cr = hi - lo;
    if (cr <= 0) return;
    for (int i = threadIdx.x; i < cr; i += 256) h[i] = 0;
    __syncthreads();
    const int chunk = (((E + nrep - 1) / nrep) + 1023) & ~1023;
    const int ebeg = rep * chunk;
    const int eend = min(E, ebeg + chunk);
    if ((E & 3) == 0) {
        for (int e = ebeg + (int)threadIdx.x * 4; e < eend; e += 1024) {
            i32x4 d4 = __builtin_nontemporal_load((const i32x4*)(dst + e));
            if (d4.x >= lo && d4.x < hi) atomicAdd(&h[d4.x - lo], 1);
            if (d4.y >= lo && d4.y < hi) atomicAdd(&h[d4.y - lo], 1);
            if (d4.z >= lo && d4.z < hi) atomicAdd(&h[d4.z - lo], 1);
            if (d4.w >= lo && d4.w < hi) atomicAdd(&h[d4.w - lo], 1);
        }
    } else {
        for (int e = ebeg + (int)threadIdx.x; e < eend; e += 256) {
            int d = __builtin_nontemporal_load(&dst[e]);
            if (d >= lo && d < hi) atomicAdd(&h[d - lo], 1);
        }
    }
    __syncthreads();
    int* po = partial + (size_t)rep * n + lo;
    for (int i = threadIdx.x; i < cr; i += 256) po[i] = h[i];
}

// ---------------- scan: per-rep bases + cnt + exclusive rowptr ----------------

__global__ __launch_bounds__(512) void k_scan1(
    const int* __restrict__ partial, int nrep, int n,
    int* __restrict__ cnt, int* __restrict__ rowptr, int* __restrict__ bsum,
    int* __restrict__ base)
{
    __shared__ int part[512];
    const int t = threadIdx.x;
    const int i = blockIdx.x * 512 + t;
    int own = 0;
    if (i < n) {
        for (int r = 0; r < nrep; ++r) {
            base[(size_t)r * n + i] = own;            // within-node prefix over reps
            own += partial[(size_t)r * n + i];
        }
        cnt[i] = own;
    }
    part[t] = own;
    __syncthreads();
#pragma unroll
    for (int off = 1; off < 512; off <<= 1) {
        int v = (t >= off) ? part[t - off] : 0;
        __syncthreads();
        part[t] += v;
        __syncthreads();
    }
    if (i < n) rowptr[i] = part[t] - own;
    if (t == 511) bsum[blockIdx.x] = part[511];
}

__global__ __launch_bounds__(256) void k_scan2(const int* __restrict__ bsum, int nb,
                                               int* __restrict__ bofs) {
    __shared__ int part[256];
    const int t = threadIdx.x;
    int own = (t < nb) ? bsum[t] : 0;
    part[t] = own;
    __syncthreads();
#pragma unroll
    for (int off = 1; off < 256; off <<= 1) {
        int v = (t >= off) ? part[t - off] : 0;
        __syncthreads();
        part[t] += v;
        __syncthreads();
    }
    if (t < nb) bofs[t] = part[t] - own;
}

__global__ void k_scan3(const int* __restrict__ cnt, int n, int E,
                        const int* __restrict__ bofs, int* __restrict__ rowptr,
                        int* __restrict__ cursor, float* __restrict__ dinv) {
    int i = blockIdx.x * blockDim.x + threadIdx.x;
    if (i >= n) return;
    int rp = rowptr[i] + bofs[i >> 9];
    rowptr[i] = rp;
    cursor[i] = rp;                       // used only by fallback fill
    dinv[i] = rsqrtf((float)(cnt[i] + 1));
    if (i == 0) rowptr[n] = E;
}

// ---------------- CSR fill: LDS cursors, NO global atomics ----------------

__global__ __launch_bounds__(256) void k_fill_np(
    const int* __restrict__ src, const int* __restrict__ dst, int E, int n, int nrep,
    const int* __restrict__ rowptr, const int* __restrict__ base, int* __restrict__ csr)
{
    __shared__ int cur[HIST_RANGE];
    const int cls = blockIdx.x & 7;
    const int rep = blockIdx.x >> 3;
    const int range = (n + 7) >> 3;
    const int lo = cls * range;
    const int hi = min(n, lo + range);
    const int cr = hi - lo;
    if (cr <= 0) return;
    const int* bp = base + (size_t)rep * n + lo;
    for (int i = threadIdx.x; i < cr; i += 256) cur[i] = rowptr[lo + i] + bp[i];
    __syncthreads();
    const int chunk = (((E + nrep - 1) / nrep) + 1023) & ~1023;
    const int ebeg = rep * chunk;
    const int eend = min(E, ebeg + chunk);
    if ((E & 3) == 0) {
        for (int e = ebeg + (int)threadIdx.x * 4; e < eend; e += 1024) {
            i32x4 d4 = __builtin_nontemporal_load((const i32x4*)(dst + e));
            i32x4 s4 = __builtin_nontemporal_load((const i32x4*)(src + e));
            if (d4.x >= lo && d4.x < hi) { int p = atomicAdd(&cur[d4.x - lo], 1); csr[p] = s4.x; }
            if (d4.y >= lo && d4.y < hi) { int p = atomicAdd(&cur[d4.y - lo], 1); csr[p] = s4.y; }
            if (d4.z >= lo && d4.z < hi) { int p = atomicAdd(&cur[d4.z - lo], 1); csr[p] = s4.z; }
            if (d4.w >= lo && d4.w < hi) { int p = atomicAdd(&cur[d4.w - lo], 1); csr[p] = s4.w; }
        }
    } else {
        for (int e = ebeg + (int)threadIdx.x; e < eend; e += 256) {
            int d = __builtin_nontemporal_load(&dst[e]);
            if (d >= lo && d < hi) {
                int s = __builtin_nontemporal_load(&src[e]);
                int p = atomicAdd(&cur[d - lo], 1);
                csr[p] = s;
            }
        }
    }
}

// fallback fill (global cursor atomics)
__global__ __launch_bounds__(256) void k_fill_part(
    const int* __restrict__ src, const int* __restrict__ dst, int E, int n,
    int* __restrict__ cursor, int* __restrict__ csr)
{
    const int range = blockIdx.x & 7;
    const int chunk = blockIdx.x >> 3;
    const int nchunks = gridDim.x >> 3;
    const int lo = (int)(((long long)n * range) >> 3);
    const int hi = (int)(((long long)n * (range + 1)) >> 3);
    for (int e = chunk * 256 + (int)threadIdx.x; e < E; e += nchunks * 256) {
        int d = __builtin_nontemporal_load(&dst[e]);
        if (d >= lo && d < hi) {
            int s = __builtin_nontemporal_load(&src[e]);
            int pos = atomicAdd(&cursor[d], 1);
            csr[pos] = s;
        }
    }
}

// ---------------- weight conversion: fp32 [K,F] -> fragment-ordered bf16 hi/lo ----------------

__global__ void k_wconv(const float* __restrict__ W, int K, int F,
                        unsigned short* __restrict__ WH, unsigned short* __restrict__ WL) {
    int idx = blockIdx.x * blockDim.x + threadIdx.x;
    int total = (K / 32) * (F / 16) * 64;
    if (idx >= total) return;
    int lane = idx & 63;
    int t = idx >> 6;
    int CT = F / 16;
    int ks = t / CT, ct = t % CT;
    int col = ct * 16 + (lane & 15);
    int kbase = ks * 32 + (lane >> 4) * 8;
    bf16x8 h, l;
#pragma unroll
    for (int j = 0; j < 8; ++j) {
        float w = W[(size_t)(kbase + j) * F + col];
        unsigned int u = __float_as_uint(w);
        unsigned short hi = (unsigned short)(u >> 16);
        float r = w - __uint_as_float((unsigned int)hi << 16);
        unsigned short lo = (unsigned short)(__float_as_uint(r) >> 16);
        h[j] = (short)hi;
        l[j] = (short)lo;
    }
    *(bf16x8*)(WH + (size_t)idx * 8) = h;
    *(bf16x8*)(WL + (size_t)idx * 8) = l;
}

// ---------------- MFMA GEMM (split-bf16, fp32-accurate) ----------------

template<int K, int F, int OMODE, bool RELU, bool BIAS, bool SUM2, bool POSTADD>
__global__ __launch_bounds__(256) void k_mgemm(
    const float* __restrict__ A0, const float* __restrict__ A1, const float* __restrict__ A2,
    const unsigned short* __restrict__ WH, const unsigned short* __restrict__ WL,
    const float* __restrict__ bias, const float* __restrict__ post,
    const float* __restrict__ dinv, void* __restrict__ outv, int n)
{
    constexpr int CT = F / 16;
    const int lane = threadIdx.x & 63;
    const int wave = threadIdx.x >> 6;
    const int row0 = blockIdx.x * 128 + wave * 32;
    const int arow = lane & 15;
    const int kgrp = lane >> 4;

    f32x4 acc[2][CT];
#pragma unroll
    for (int rt = 0; rt < 2; ++rt)
#pragma unroll
        for (int ct = 0; ct < CT; ++ct) acc[rt][ct] = (f32x4)(0.f);

#pragma unroll
    for (int ks = 0; ks < K / 32; ++ks) {
        const float* Ap; int kof;
        if constexpr (K == 128) { Ap = A0; kof = ks * 32; }
        else { int p = ks >> 2; Ap = (p == 0) ? A0 : ((p == 1) ? A1 : A2); kof = (ks & 3) * 32; }

        bf16x8 ah[2], al[2];
#pragma unroll
        for (int rt = 0; rt < 2; ++rt) {
            int row = row0 + rt * 16 + arow;
            if (row >= n) row = n - 1;
            const float* p = Ap + (size_t)row * 128 + kof + kgrp * 8;
            f32x4 v0 = *(const f32x4*)p;
            f32x4 v1 = *(const f32x4*)(p + 4);
            if constexpr (SUM2) {
                const float* q = A1 + (size_t)row * 128 + kof + kgrp * 8;
                f32x4 u0 = *(const f32x4*)q;
                f32x4 u1 = *(const f32x4*)(q + 4);
                v0 += u0; v1 += u1;
            }
#pragma unroll
            for (int j = 0; j < 8; ++j) {
                float f = (j < 4) ? v0[j] : v1[j - 4];
                unsigned int u = __float_as_uint(f);
                unsigned short hi = (unsigned short)(u >> 16);
                float r = f - __uint_as_float((unsigned int)hi << 16);
                ah[rt][j] = (short)hi;
                al[rt][j] = (short)(__float_as_uint(r) >> 16);
            }
        }

#pragma unroll
        for (int ct = 0; ct < CT; ++ct) {
            size_t fo = (((size_t)ks * CT + ct) * 64 + lane) * 8;
            bf16x8 bh = *(const bf16x8*)(WH + fo);
            bf16x8 bl = *(const bf16x8*)(WL + fo);
#pragma unroll
            for (int rt = 0; rt < 2; ++rt) {
                acc[rt][ct] = __builtin_amdgcn_mfma_f32_16x16x32_bf16(ah[rt], bh, acc[rt][ct], 0, 0, 0);
                acc[rt][ct] = __builtin_amdgcn_mfma_f32_16x16x32_bf16(al[rt], bh, acc[rt][ct], 0, 0, 0);
                acc[rt][ct] = __builtin_amdgcn_mfma_f32_16x16x32_bf16(ah[rt], bl, acc[rt][ct], 0, 0, 0);
            }
        }
    }

    // epilogue: D layout col=lane&15, row=(lane>>4)*4+reg  [m89-verified]
    if constexpr (OMODE == 1) {
        unsigned short* ob = (unsigned short*)outv;
        float dv[2][4];
#pragma unroll
        for (int rt = 0; rt < 2; ++rt)
#pragma unroll
            for (int r = 0; r < 4; ++r) {
                int row = row0 + rt * 16 + kgrp * 4 + r;
                dv[rt][r] = (row < n) ? dinv[row] : 0.f;
            }
#pragma unroll
        for (int rt = 0; rt < 2; ++rt) {
#pragma unroll
            for (int ct = 0; ct < CT; ++ct) {
                int j = ct * 16 + arow;
#pragma unroll
                for (int r = 0; r < 4; ++r) {
                    int row = row0 + rt * 16 + kgrp * 4 + r;
                    if (row < n) {
                        float v = acc[rt][ct][r] * dv[rt][r];
                        unsigned int u = __float_as_uint(v);
                        u += 0x7fffu + ((u >> 16) & 1u);        // RNE
                        ob[(size_t)row * F + j] = (unsigned short)(u >> 16);
                    }
                }
            }
        }
    } else {
        float* ofp = (float*)outv;
#pragma unroll
        for (int rt = 0; rt < 2; ++rt) {
#pragma unroll
            for (int ct = 0; ct < CT; ++ct) {
                int j = ct * 16 + arow;
                float bv = 0.f;
                if constexpr (BIAS) bv = bias[j];
#pragma unroll
                for (int r = 0; r < 4; ++r) {
                    int row = row0 + rt * 16 + kgrp * 4 + r;
                    if (row < n) {
                        float v = acc[rt][ct][r];
                        if constexpr (BIAS) v += bv;
                        if constexpr (RELU) v = fmaxf(v, 0.f);
                        if constexpr (POSTADD) v += post[(size_t)row * F + j];
                        ofp[(size_t)row * F + j] = v;
                    }
                }
            }
        }
    }
}

// ---------------- GCN aggregation over pre-scaled bf16 features ----------------

__global__ __launch_bounds__(256) void k_agg_bf(
    const int* __restrict__ rowptr, const int* __restrict__ csr,
    const float* __restrict__ dinv, const unsigned short* __restrict__ hs,
    const float* __restrict__ bias, float* __restrict__ out, int n)
{
    const int node = blockIdx.x * 8 + (threadIdx.x >> 5);
    if (node >= n) return;
    const int c = threadIdx.x & 31;
    const float dd = dinv[node];
    const int beg = rowptr[node];
    const int end = rowptr[node + 1];

    ushort4 sv = *(const ushort4*)(hs + (size_t)node * 128 + c * 4);
    float a0 = __uint_as_float((unsigned int)sv.x << 16);
    float a1 = __uint_as_float((unsigned int)sv.y << 16);
    float a2 = __uint_as_float((unsigned int)sv.z << 16);
    float a3 = __uint_as_float((unsigned int)sv.w << 16);

    int j = beg;
    for (; j + 3 < end; j += 4) {
        int s0 = csr[j], s1 = csr[j + 1], s2 = csr[j + 2], s3 = csr[j + 3];
        ushort4 v0 = *(const ushort4*)(hs + (size_t)s0 * 128 + c * 4);
        ushort4 v1 = *(const ushort4*)(hs + (size_t)s1 * 128 + c * 4);
        ushort4 v2 = *(const ushort4*)(hs + (size_t)s2 * 128 + c * 4);
        ushort4 v3 = *(const ushort4*)(hs + (size_t)s3 * 128 + c * 4);
        a0 += __uint_as_float((unsigned int)v0.x << 16);
        a1 += __uint_as_float((unsigned int)v0.y << 16);
        a2 += __uint_as_float((unsigned int)v0.z << 16);
        a3 += __uint_as_float((unsigned int)v0.w << 16);
        a0 += __uint_as_float((unsigned int)v1.x << 16);
        a1 += __uint_as_float((unsigned int)v1.y << 16);
        a2 += __uint_as_float((unsigned int)v1.z << 16);
        a3 += __uint_as_float((unsigned int)v1.w << 16);
        a0 += __uint_as_float((unsigned int)v2.x << 16);
        a1 += __uint_as_float((unsigned int)v2.y << 16);
        a2 += __uint_as_float((unsigned int)v2.z << 16);
        a3 += __uint_as_float((unsigned int)v2.w << 16);
        a0 += __uint_as_float((unsigned int)v3.x << 16);
        a1 += __uint_as_float((unsigned int)v3.y << 16);
        a2 += __uint_as_float((unsigned int)v3.z << 16);
        a3 += __uint_as_float((unsigned int)v3.w << 16);
    }
    for (; j < end; ++j) {
        int s = csr[j];
        ushort4 v = *(const ushort4*)(hs + (size_t)s * 128 + c * 4);
        a0 += __uint_as_float((unsigned int)v.x << 16);
        a1 += __uint_as_float((unsigned int)v.y << 16);
        a2 += __uint_as_float((unsigned int)v.z << 16);
        a3 += __uint_as_float((unsigned int)v.w << 16);
    }

    float4 bv = ((const float4*)bias)[c];
    float4 o;
    o.x = fmaxf(fmaf(dd, a0, bv.x), 0.f);
    o.y = fmaxf(fmaf(dd, a1, bv.y), 0.f);
    o.z = fmaxf(fmaf(dd, a2, bv.z), 0.f);
    o.w = fmaxf(fmaf(dd, a3, bv.w), 0.f);
    ((float4*)out)[(size_t)node * 32 + c] = o;
}

// ---------------- final small GEMM [n,64]@[64,10] ----------------

__global__ __launch_bounds__(256) void k_final(const float* __restrict__ z7, const float* __restrict__ Wo,
                        const float* __restrict__ bo, float* __restrict__ out, int n) {
    __shared__ float Wos[64][10];
    __shared__ float bos[10];
    if (threadIdx.x < 64) {
#pragma unroll
        for (int j = 0; j < 10; ++j) Wos[threadIdx.x][j] = Wo[threadIdx.x * 10 + j];
        if (threadIdx.x < 10) bos[threadIdx.x] = bo[threadIdx.x];
    }
    __syncthreads();
    int idx = blockIdx.x * blockDim.x + threadIdx.x;
    if (idx >= n * 10) return;
    int row = idx / 10, j = idx % 10;
    const float* zr = z7 + (size_t)row * 64;
    float acc = bos[j];
#pragma unroll
    for (int k = 0; k < 64; ++k) acc = fmaf(zr[k], Wos[k][j], acc);
    out[idx] = acc;
}

// ---------------- launch ----------------

extern "C" void kernel_launch(void* const* d_in, const int* in_sizes, int n_in,
                              void* d_out, int out_size, void* d_ws, size_t ws_size,
                              hipStream_t stream) {
    const float* x   = (const float*)d_in[0];
    const float* gx  = (const float*)d_in[1];
    const void*  ei  = d_in[2];
    const float* W1  = (const float*)d_in[3];  const float* b1  = (const float*)d_in[4];
    const float* Wdr = (const float*)d_in[5];  const float* bdr = (const float*)d_in[6];
    const float* Wg1 = (const float*)d_in[7];  const float* bg1 = (const float*)d_in[8];
    const float* Wg2 = (const float*)d_in[9];  const float* bg2 = (const float*)d_in[10];
    const float* W2  = (const float*)d_in[11]; const float* b2  = (const float*)d_in[12];
    const float* W3  = (const float*)d_in[13]; const float* b3  = (const float*)d_in[14];
    const float* Wo  = (const float*)d_in[15]; const float* bo  = (const float*)d_in[16];
    float* out = (float*)d_out;
    const int n = in_sizes[0] / 128;
    const int E = in_sizes[2] / 2;
    const int twoE = 2 * E;
    const int nb = (n + 511) / 512;
    const int NREP = 64;

    char* ws = (char*)d_ws;
    size_t off = 0;
    auto alloc = [&](size_t bytes) -> void* {
        void* p = ws + off;
        off = (off + bytes + 255) & ~(size_t)255;
        return p;
    };
    int*   flag   = (int*)  alloc(256);
    int*   cnt    = (int*)  alloc((size_t)n * 4);
    int*   rowptr = (int*)  alloc(((size_t)n + 1) * 4);
    int*   cursor = (int*)  alloc((size_t)n * 4);
    float* dinv   = (float*)alloc((size_t)n * 4);
    int*   bsum   = (int*)  alloc(1024);
    int*   bofs   = (int*)  alloc(1024);
    int*   es     = (int*)  alloc((size_t)twoE * 4);
    int*   ed     = es + E;
    int*   csr    = (int*)  alloc((size_t)E * 4);
    int*   partial= (int*)  alloc((size_t)NREP * n * 4);
    int*   base   = (int*)  alloc((size_t)NREP * n * 4);
    unsigned short* W1H  = (unsigned short*)alloc(256 * 128 * 2);
    unsigned short* W1L  = (unsigned short*)alloc(256 * 128 * 2);
    unsigned short* WdrH = (unsigned short*)alloc(128 * 128 * 2);
    unsigned short* WdrL = (unsigned short*)alloc(128 * 128 * 2);
    unsigned short* Wg1H = (unsigned short*)alloc(128 * 128 * 2);
    unsigned short* Wg1L = (unsigned short*)alloc(128 * 128 * 2);
    unsigned short* Wg2H = (unsigned short*)alloc(128 * 128 * 2);
    unsigned short* Wg2L = (unsigned short*)alloc(128 * 128 * 2);
    unsigned short* W2H  = (unsigned short*)alloc(384 * 128 * 2);
    unsigned short* W2L  = (unsigned short*)alloc(384 * 128 * 2);
    unsigned short* W3H  = (unsigned short*)alloc(128 * 64 * 2);
    unsigned short* W3L  = (unsigned short*)alloc(128 * 64 * 2);
    unsigned short* HS1  = (unsigned short*)alloc((size_t)n * 128 * 2);
    unsigned short* HS2  = (unsigned short*)alloc((size_t)n * 128 * 2);
    float* B0 = (float*)alloc((size_t)n * 128 * 4); // z
    float* B1 = (float*)alloc((size_t)n * 128 * 4); // z0 -> z7
    float* B2 = (float*)alloc((size_t)n * 128 * 4); // t
    float* B3 = (float*)alloc((size_t)n * 128 * 4); // z1
    float* B4 = (float*)alloc((size_t)n * 128 * 4); // z2
    (void)ws_size; (void)n_in; (void)out_size;

    // edge prep + CSR build
    k_detect<<<1, 64, 0, stream>>>((const unsigned int*)ei, flag);
    k_convert<<<(twoE / 2 + 255) / 256, 256, 0, stream>>>(ei, twoE, flag, es);
    if (n <= 8 * HIST_RANGE) {
        k_hist_part<<<8 * NREP, 256, 0, stream>>>(ed, E, n, NREP, partial);
        k_scan1<<<nb, 512, 0, stream>>>(partial, NREP, n, cnt, rowptr, bsum, base);
        k_scan2<<<1, 256, 0, stream>>>(bsum, nb, bofs);
        k_scan3<<<(n + 255) / 256, 256, 0, stream>>>(cnt, n, E, bofs, rowptr, cursor, dinv);
        k_fill_np<<<8 * NREP, 256, 0, stream>>>(es, ed, E, n, NREP, rowptr, base, csr);
    } else {
        hipMemsetAsync(cnt, 0, (size_t)n * 4, stream);
        k_hist_atomic<<<(E + 255) / 256, 256, 0, stream>>>(ed, E, cnt);
        k_scan1<<<nb, 512, 0, stream>>>(cnt, 1, n, cnt, rowptr, bsum, base);
        k_scan2<<<1, 256, 0, stream>>>(bsum, nb, bofs);
        k_scan3<<<(n + 255) / 256, 256, 0, stream>>>(cnt, n, E, bofs, rowptr, cursor, dinv);
        k_fill_part<<<2048, 256, 0, stream>>>(es, ed, E, n, cursor, csr);
    }

    // weight conversions (tiny)
    k_wconv<<<(256 * 128 + 255) / 256, 256, 0, stream>>>(W1,  256, 128, W1H,  W1L);
    k_wconv<<<(128 * 128 + 255) / 256, 256, 0, stream>>>(Wdr, 128, 128, WdrH, WdrL);
    k_wconv<<<(128 * 128 + 255) / 256, 256, 0, stream>>>(Wg1, 128, 128, Wg1H, Wg1L);
    k_wconv<<<(128 * 128 + 255) / 256, 256, 0, stream>>>(Wg2, 128, 128, Wg2H, Wg2L);
    k_wconv<<<(384 * 128 + 255) / 256, 256, 0, stream>>>(W2,  384, 128, W2H,  W2L);
    k_wconv<<<(128 * 64  + 255) / 256, 256, 0, stream>>>(W3,  128, 64,  W3H,  W3L);

    const int gm = (n + 127) / 128;
    const int ga = (n + 7) / 8;
    // z = relu([x|gx] @ W1 + b1)
    k_mgemm<256, 128, 0, true,  true,  false, false><<<gm, 256, 0, stream>>>(x, gx, nullptr, W1H, W1L, b1, nullptr, nullptr, B0, n);
    // z0 = z @ Wdr + bdr
    k_mgemm<128, 128, 0, false, true,  false, false><<<gm, 256, 0, stream>>>(B0, nullptr, nullptr, WdrH, WdrL, bdr, nullptr, nullptr, B1, n);
    // hs1 = dinv * ((z + gx) @ Wg1)   [bf16]
    k_mgemm<128, 128, 1, false, false, true,  false><<<gm, 256, 0, stream>>>(B0, gx, nullptr, Wg1H, Wg1L, nullptr, nullptr, dinv, HS1, n);
    // z1 = relu(dinv * (hs1[d] + sum hs1[s]) + bg1)
    k_agg_bf<<<ga, 256, 0, stream>>>(rowptr, csr, dinv, HS1, bg1, B3, n);
    // hs2 = dinv * (z1 @ Wg2)   [bf16]
    k_mgemm<128, 128, 1, false, false, false, false><<<gm, 256, 0, stream>>>(B3, nullptr, nullptr, Wg2H, Wg2L, nullptr, nullptr, dinv, HS2, n);
    // z2 = relu(dinv * (hs2[d] + sum hs2[s]) + bg2)
    k_agg_bf<<<ga, 256, 0, stream>>>(rowptr, csr, dinv, HS2, bg2, B4, n);
    // t = relu([z|z1|z2] @ W2 + b2) + z0
    k_mgemm<384, 128, 0, true,  true,  false, true ><<<gm, 256, 0, stream>>>(B0, B3, B4, W2H, W2L, b2, B1, nullptr, B2, n);
    // z7 = relu(t @ W3 + b3)
    k_mgemm<128, 64,  0, true,  true,  false, false><<<gm, 256, 0, stream>>>(B2, nullptr, nullptr, W3H, W3L, b3, nullptr, nullptr, B1, n);
    // out = z7 @ Wo + bo
    k_final<<<(n * 10 + 255) / 256, 256, 0, stream>>>(B1, Wo, bo, out, n);
}